// Round 16
// baseline (80.963 us; speedup 1.0000x reference)
//
#include <hip/hip_runtime.h>

#define KTOT 65536
#define QN 16
#define DN 64
#define BN 8
#define TILE 256

// smem layout (floats) — 9216 floats = 36,864 B
#define QS_OFF 0                    // Q scaled: [16][64]                 = 1024 floats
#define R0_OFF 1024                 // K quarter region 0: [256][16]      = 4096
#define R1_OFF 5120                 // K quarter region 1: [256][16]      = 4096
                                    // R1 doubles as A: per-wave [16][64] slices (wave-private)
#define SMEM_FLOATS 9216

typedef float f2v __attribute__((ext_vector_type(2)));
typedef float f4v __attribute__((ext_vector_type(4)));

// Packed dual-FP32 math (VOP3P, CDNA): d = a*b (lo,hi) / d += a*b (lo,hi).
#define PK_MUL(d, a, b) asm("v_pk_mul_f32 %0, %1, %2"     : "=v"(d) : "v"(a), "v"(b))
#define PK_FMA(d, a, b) asm("v_pk_fma_f32 %0, %1, %2, %0" : "+v"(d) : "v"(a), "v"(b))

// async global->LDS, 16B per lane; dest = wave-uniform base + lane*16
__device__ __forceinline__ void gload_lds16(const float* g, float* l)
{
    __builtin_amdgcn_global_load_lds(
        (const __attribute__((address_space(1))) void*)g,
        (__attribute__((address_space(3))) void*)l, 16, 0, 0);
}

// Counted wait. "memory" clobber = compiler fence (exact vmcnt ledger);
// sched_barrier(0) stops reg-only hoisting (rule #18). Straight-line use only (r10 lesson).
#define WAIT_VM(N)  do { asm volatile("s_waitcnt vmcnt(" #N ")" ::: "memory");      \
                         __builtin_amdgcn_sched_barrier(0); } while (0)
#define LGKM0()     do { asm volatile("s_waitcnt lgkmcnt(0)" ::: "memory");         \
                         __builtin_amdgcn_sched_barrier(0); } while (0)

// WAVE-PRIVATE staging (verified r7/r9): wave wv stages ITS OWN rows 64wv..64wv+63
// of one K quarter (16 float cols; qo4 = quarter*4 in float4 units); exactly 4 gload_lds.
// Source pre-swizzled: global col = (lane&3) ^ ((row>>1)&3); read applies same XOR.
#define STAGE_WV(RX, kb4, qo4)                                                      \
    {                                                                               \
        _Pragma("unroll")                                                           \
        for (int j = 0; j < 4; ++j) {                                               \
            const int r_ = (wv << 6) + (j << 4) + (lane >> 2);                      \
            const int p_ = (lane & 3) ^ ((r_ >> 1) & 3);                            \
            gload_lds16((const float*)((kb4) + r_ * 16 + (qo4) + p_),               \
                        (float*)(((float4*)&smem[RX]) + ((wv << 8) + (j << 6) + lane))); \
        }                                                                           \
    }

// dot quarter qt: thread owns row tid; 16-wide packed chain per q (r15-proven).
#define DOT_Q(qt, RX)                                                               \
    {                                                                               \
        __builtin_amdgcn_s_setprio(1);                                              \
        f4v kvv[4];                                                                 \
        _Pragma("unroll")                                                           \
        for (int cc = 0; cc < 4; ++cc)                                              \
            kvv[cc] = ((const f4v*)&smem[RX])[tid * 4 + (cc ^ fr)];                 \
        _Pragma("unroll")                                                           \
        for (int q = 0; q < QN; ++q) {                                              \
            const f4v qv0 = *(const f4v*)&smem[QS_OFF + q * DN + (qt) * 16 + 0];    \
            const f4v qv1 = *(const f4v*)&smem[QS_OFF + q * DN + (qt) * 16 + 4];    \
            const f4v qv2 = *(const f4v*)&smem[QS_OFF + q * DN + (qt) * 16 + 8];    \
            const f4v qv3 = *(const f4v*)&smem[QS_OFF + q * DN + (qt) * 16 + 12];   \
            f2v t;                                                                  \
            PK_MUL(t, kvv[0].xy, qv0.xy);                                           \
            PK_FMA(t, kvv[0].zw, qv0.zw);                                           \
            PK_FMA(t, kvv[1].xy, qv1.xy);                                           \
            PK_FMA(t, kvv[1].zw, qv1.zw);                                           \
            PK_FMA(t, kvv[2].xy, qv2.xy);                                           \
            PK_FMA(t, kvv[2].zw, qv2.zw);                                           \
            PK_FMA(t, kvv[3].xy, qv3.xy);                                           \
            PK_FMA(t, kvv[3].zw, qv3.zw);                                           \
            s[q] += t.x + t.y;                                                      \
        }                                                                           \
        __builtin_amdgcn_s_setprio(0);                                              \
    }

// ------------- Fused: QK^T + softmax(Q) + attn write + PV partials ----------
// Round-16 = round 15 (80.8us best) + V prefetch depth 1 -> 2 in PV, register-neutral:
// batch1 (vb2) issued right after the A-writes (where s[16] dies -> no 64-VGPR cliff
// crossing), batch k+2 (vc2) issued during batch k's compute. Steady-state V cover
// ~224 -> ~500 cyc. Theory: with issue-saturation refuted (r15: -31% VALU slots -> -3%)
// and K-stage exposure refuted (r11), the depth-1 V chain in PV (half of V misses L3,
// ~900cy) is the last uncovered per-wave latency chain. All WAIT ledgers unchanged.
__global__ __launch_bounds__(256, 3) void fused_attn(
    const float* __restrict__ query, const float* __restrict__ key,
    const float* __restrict__ value, float* __restrict__ attn,
    float* __restrict__ upart, int NCH, int ntiles)
{
    __shared__ float smem[SMEM_FLOATS];
    const int b    = blockIdx.y;
    const int c    = blockIdx.x;
    const int tid  = threadIdx.x;
    const int wv   = tid >> 6;
    const int lane = tid & 63;
    const int chunk = ntiles * TILE;
    const int fr   = (tid >> 1) & 3;
    const int AW   = R1_OFF + wv * (QN * 64);   // A: own 4KB slice of R1

    // Q -> LDS (scaled), ONE barrier; stages issued after it are never drained again
    {
        float4 qv = reinterpret_cast<const float4*>(query + (size_t)b * QN * DN)[tid];
        qv.x *= 0.125f; qv.y *= 0.125f; qv.z *= 0.125f; qv.w *= 0.125f;
        reinterpret_cast<float4*>(&smem[QS_OFF])[tid] = qv;
    }
    __syncthreads();

    {
        const float4* kb4 = reinterpret_cast<const float4*>(
            key + ((size_t)b * KTOT + c * chunk) * DN);
        STAGE_WV(R0_OFF, kb4, 0);   // tile0 q0
        STAGE_WV(R1_OFF, kb4, 4);   // tile0 q1
        __builtin_amdgcn_sched_barrier(0);
    }

    float U[QN];
    #pragma unroll
    for (int q = 0; q < QN; ++q) U[q] = 0.f;

    for (int t = 0; t < ntiles; ++t) {
        const int krow0 = c * chunk + t * TILE;
        const float4* kb4  = reinterpret_cast<const float4*>(
            key + ((size_t)b * KTOT + krow0) * DN);
        const float4* kb4n = kb4 + TILE * 16;                         // next tile
        const float*  vptr = value + ((size_t)b * KTOT + krow0 + wv * 64) * DN + lane;

        float s[QN];
        #pragma unroll
        for (int q = 0; q < QN; ++q) s[q] = 0.f;

        // ledger (wave-local, r9-proven): top of tile outstanding = stores(old)+q0(4)+q1(4)
        WAIT_VM(4);                                                   // q0 ready
        DOT_Q(0, R0_OFF);
        LGKM0(); STAGE_WV(R0_OFF, kb4, 8);                            // q2 -> R0
        __builtin_amdgcn_sched_barrier(0);

        WAIT_VM(4);                                                   // q1 ready (q2 may remain)
        DOT_Q(1, R1_OFF);
        LGKM0(); STAGE_WV(R1_OFF, kb4, 12);                           // q3 -> R1
        __builtin_amdgcn_sched_barrier(0);

        WAIT_VM(4);                                                   // q2 ready (q3 may remain)
        DOT_Q(2, R0_OFF);

        // V batch 0 (8 loads into 4 packed pairs) -> rides through dot q3 + softmax
        f2v va2[4];
        #pragma unroll
        for (int i = 0; i < 4; ++i) {
            va2[i].x = vptr[(size_t)(2 * i) * DN];
            va2[i].y = vptr[(size_t)(2 * i + 1) * DN];
        }
        __builtin_amdgcn_sched_barrier(0);
        WAIT_VM(8);                                                   // q3 ready (va 8 younger)
        DOT_Q(3, R1_OFF);

        // ---- softmax over the 16 queries (thread-local, k = krow0 + tid) ----
        float m = s[0];
        #pragma unroll
        for (int q = 1; q < QN; ++q) m = fmaxf(m, s[q]);
        float sum = 0.f;
        #pragma unroll
        for (int q = 0; q < QN; ++q) { s[q] = __expf(s[q] - m); sum += s[q]; }
        const float inv = 1.0f / sum;
        {
            float* ab = attn + (size_t)b * QN * KTOT + krow0 + tid;
            #pragma unroll
            for (int q = 0; q < QN; ++q) {
                const float a = s[q] * inv;
                __builtin_nontemporal_store(a, ab + (size_t)q * KTOT);
                smem[AW + q * 64 + lane] = a;        // own slice; dot-q3 reads already retired
            }
        }

        // V batch 1 issued here (s[] just died -> register-neutral); cover = pre-PV tail
        f2v vb2[4];
        #pragma unroll
        for (int i = 0; i < 4; ++i) {
            vb2[i].x = vptr[(size_t)(8 + 2 * i) * DN];
            vb2[i].y = vptr[(size_t)(8 + 2 * i + 1) * DN];
        }
        __builtin_amdgcn_sched_barrier(0);

        // ---- PV: packed 8-wide chains, V prefetch 2 batches deep ----
        #pragma unroll 1
        for (int kk = 0; kk < 64; kk += 8) {
            f2v vc2[4];
            const int nxt = kk + 16;
            if (nxt < 64) {
                #pragma unroll
                for (int i = 0; i < 4; ++i) {
                    vc2[i].x = vptr[(size_t)(nxt + 2 * i) * DN];
                    vc2[i].y = vptr[(size_t)(nxt + 2 * i + 1) * DN];
                }
            }
            __builtin_amdgcn_s_setprio(1);
            #pragma unroll
            for (int q = 0; q < QN; ++q) {
                const f4v av0 = *(const f4v*)&smem[AW + q * 64 + kk];     // uniform bcast
                const f4v av1 = *(const f4v*)&smem[AW + q * 64 + kk + 4]; // uniform bcast
                f2v t;
                PK_MUL(t, av0.xy, va2[0]);
                PK_FMA(t, av0.zw, va2[1]);
                PK_FMA(t, av1.xy, va2[2]);
                PK_FMA(t, av1.zw, va2[3]);
                U[q] += t.x + t.y;
            }
            __builtin_amdgcn_s_setprio(0);
            #pragma unroll
            for (int i = 0; i < 4; ++i) { va2[i] = vb2[i]; vb2[i] = vc2[i]; }
        }

        // next tile's q0,q1 issued at PV end (r9 schedule; hoist tested r11: neutral)
        if (t + 1 < ntiles) {
            LGKM0();
            STAGE_WV(R0_OFF, kb4n, 0);
            STAGE_WV(R1_OFF, kb4n, 4);
            __builtin_amdgcn_sched_barrier(0);
        }
    }

    // ---- block reduction: U across 4 waves (R0 region) ----
    __syncthreads();                                   // full drain (outside main loop)
    #pragma unroll
    for (int q = 0; q < QN; ++q)
        smem[R0_OFF + (wv * QN + q) * DN + lane] = U[q];
    __syncthreads();

    {
        const int q = tid >> 4, d0 = (tid & 15) * 4;
        const float4 r0 = *reinterpret_cast<const float4*>(&smem[R0_OFF + (0 * QN + q) * DN + d0]);
        const float4 r1 = *reinterpret_cast<const float4*>(&smem[R0_OFF + (1 * QN + q) * DN + d0]);
        const float4 r2 = *reinterpret_cast<const float4*>(&smem[R0_OFF + (2 * QN + q) * DN + d0]);
        const float4 r3 = *reinterpret_cast<const float4*>(&smem[R0_OFF + (3 * QN + q) * DN + d0]);
        float4 rs;
        rs.x = r0.x + r1.x + r2.x + r3.x;
        rs.y = r0.y + r1.y + r2.y + r3.y;
        rs.z = r0.z + r1.z + r2.z + r3.z;
        rs.w = r0.w + r1.w + r2.w + r3.w;
        *reinterpret_cast<float4*>(
            &upart[(((size_t)b * NCH + c) * QN + q) * DN + d0]) = rs;
    }
}

// ------------- Finalize: norm from attn matrix; out = sum_c U / (norm + eps) -----------
// grid (8,16). norm[b][q] = sum_k attn[b][q][k] — L2/L3-resident re-read (just written).
__global__ __launch_bounds__(256) void k3_fin(
    const float* __restrict__ attn, const float* __restrict__ upart,
    float* __restrict__ out, int NCH)
{
    const int b = blockIdx.x, q = blockIdx.y;
    const int tid = threadIdx.x;
    const int wv = tid >> 6, lane = tid & 63;

    // norm: coalesced float4 sweep of this (b,q) attn row
    const float4* ap = reinterpret_cast<const float4*>(attn + ((size_t)b * QN + q) * KTOT);
    float nv = 0.f;
    #pragma unroll 4
    for (int i = tid; i < KTOT / 4; i += 256) {
        const float4 a = ap[i];
        nv += (a.x + a.y) + (a.z + a.w);
    }
    #pragma unroll
    for (int off = 1; off < 64; off <<= 1) nv += __shfl_xor(nv, off, 64);
    __shared__ float nred[4];
    if (lane == 0) nred[wv] = nv;

    // U: wave wv strides chunks, lane = d (coalesced)
    float acc = 0.f;
    for (int c = wv; c < NCH; c += 4)
        acc += upart[(((size_t)b * NCH + c) * QN + q) * DN + lane];
    __shared__ float ured[4][DN];
    ured[wv][lane] = acc;
    __syncthreads();

    if (tid < DN) {
        const float n   = nred[0] + nred[1] + nred[2] + nred[3];
        const float inv = 1.0f / (n + 1e-8f);
        const float u   = ured[0][tid] + ured[1][tid] + ured[2][tid] + ured[3][tid];
        out[((size_t)b * QN + q) * DN + tid] = u * inv;
    }
}

extern "C" void kernel_launch(void* const* d_in, const int* in_sizes, int n_in,
                              void* d_out, int out_size, void* d_ws, size_t ws_size,
                              hipStream_t stream)
{
    const float* query = (const float*)d_in[0];
    const float* key   = (const float*)d_in[1];
    const float* value = (const float*)d_in[2];

    float* out  = (float*)d_out;                          // [8,16,64]
    float* attn = (float*)d_out + (size_t)BN * QN * DN;   // [8,1,16,65536]

    int NCH = 128;                                        // 1024 blocks (round-9 proven)
    while (NCH > 8 && (size_t)BN * NCH * QN * DN * 4 > ws_size) NCH >>= 1;
    const int ntiles = (KTOT / NCH) / TILE;

    float* upart = (float*)d_ws;                          // [8][NCH][16][64]

    fused_attn<<<dim3(NCH, BN), 256, 0, stream>>>(query, key, value, attn,
                                                  upart, NCH, ntiles);
    k3_fin   <<<dim3(BN, QN), 256, 0, stream>>>(attn, upart, out, NCH);
}

// Round 17
// 77.101 us; speedup vs baseline: 1.0501x; 1.0501x over previous
//
#include <hip/hip_runtime.h>

#define KTOT 65536
#define QN 16
#define DN 64
#define BN 8
#define TILE 256

// smem layout (floats) — 9216 floats = 36,864 B
#define QS_OFF 0                    // Q scaled: [16][64]                 = 1024 floats
#define R0_OFF 1024                 // K quarter region 0: [256][16]      = 4096
#define R1_OFF 5120                 // K quarter region 1: [256][16]      = 4096
                                    // R1 doubles as A: per-wave [16][64] slices (wave-private)
#define SMEM_FLOATS 9216

typedef float f2v __attribute__((ext_vector_type(2)));
typedef float f4v __attribute__((ext_vector_type(4)));

// Packed dual-FP32 math (VOP3P, CDNA): d = a*b (lo,hi) / d += a*b (lo,hi).
#define PK_MUL(d, a, b) asm("v_pk_mul_f32 %0, %1, %2"     : "=v"(d) : "v"(a), "v"(b))
#define PK_FMA(d, a, b) asm("v_pk_fma_f32 %0, %1, %2, %0" : "+v"(d) : "v"(a), "v"(b))

// async global->LDS, 16B per lane; dest = wave-uniform base + lane*16
__device__ __forceinline__ void gload_lds16(const float* g, float* l)
{
    __builtin_amdgcn_global_load_lds(
        (const __attribute__((address_space(1))) void*)g,
        (__attribute__((address_space(3))) void*)l, 16, 0, 0);
}

// Counted wait. "memory" clobber = compiler fence (exact vmcnt ledger);
// sched_barrier(0) stops reg-only hoisting (rule #18). Straight-line use only (r10 lesson).
#define WAIT_VM(N)  do { asm volatile("s_waitcnt vmcnt(" #N ")" ::: "memory");      \
                         __builtin_amdgcn_sched_barrier(0); } while (0)
#define LGKM0()     do { asm volatile("s_waitcnt lgkmcnt(0)" ::: "memory");         \
                         __builtin_amdgcn_sched_barrier(0); } while (0)

// WAVE-PRIVATE staging (verified r7/r9): wave wv stages ITS OWN rows 64wv..64wv+63
// of one K quarter (16 float cols; qo4 = quarter*4 in float4 units); exactly 4 gload_lds.
// Source pre-swizzled: global col = (lane&3) ^ ((row>>1)&3); read applies same XOR.
#define STAGE_WV(RX, kb4, qo4)                                                      \
    {                                                                               \
        _Pragma("unroll")                                                           \
        for (int j = 0; j < 4; ++j) {                                               \
            const int r_ = (wv << 6) + (j << 4) + (lane >> 2);                      \
            const int p_ = (lane & 3) ^ ((r_ >> 1) & 3);                            \
            gload_lds16((const float*)((kb4) + r_ * 16 + (qo4) + p_),               \
                        (float*)(((float4*)&smem[RX]) + ((wv << 8) + (j << 6) + lane))); \
        }                                                                           \
    }

// dot quarter qt: thread owns row tid; 16-wide packed chain per q (r15-proven).
#define DOT_Q(qt, RX)                                                               \
    {                                                                               \
        __builtin_amdgcn_s_setprio(1);                                              \
        f4v kvv[4];                                                                 \
        _Pragma("unroll")                                                           \
        for (int cc = 0; cc < 4; ++cc)                                              \
            kvv[cc] = ((const f4v*)&smem[RX])[tid * 4 + (cc ^ fr)];                 \
        _Pragma("unroll")                                                           \
        for (int q = 0; q < QN; ++q) {                                              \
            const f4v qv0 = *(const f4v*)&smem[QS_OFF + q * DN + (qt) * 16 + 0];    \
            const f4v qv1 = *(const f4v*)&smem[QS_OFF + q * DN + (qt) * 16 + 4];    \
            const f4v qv2 = *(const f4v*)&smem[QS_OFF + q * DN + (qt) * 16 + 8];    \
            const f4v qv3 = *(const f4v*)&smem[QS_OFF + q * DN + (qt) * 16 + 12];   \
            f2v t;                                                                  \
            PK_MUL(t, kvv[0].xy, qv0.xy);                                           \
            PK_FMA(t, kvv[0].zw, qv0.zw);                                           \
            PK_FMA(t, kvv[1].xy, qv1.xy);                                           \
            PK_FMA(t, kvv[1].zw, qv1.zw);                                           \
            PK_FMA(t, kvv[2].xy, qv2.xy);                                           \
            PK_FMA(t, kvv[2].zw, qv2.zw);                                           \
            PK_FMA(t, kvv[3].xy, qv3.xy);                                           \
            PK_FMA(t, kvv[3].zw, qv3.zw);                                           \
            s[q] += t.x + t.y;                                                      \
        }                                                                           \
        __builtin_amdgcn_s_setprio(0);                                              \
    }

// ------------- Fused: QK^T + softmax(Q) + attn write + PV partials ----------
// Round-17: fused kernel is round-15 VERBATIM (80.8us champion; r16's depth-2 V prefetch
// was null and is reverted). The round-17 change is entirely outside this kernel: the
// norm sweep moves from half-occupancy k3_fin (128 blocks reading 33.5MB) to a new
// full-machine k_norm kernel (1024 blocks).
__global__ __launch_bounds__(256, 3) void fused_attn(
    const float* __restrict__ query, const float* __restrict__ key,
    const float* __restrict__ value, float* __restrict__ attn,
    float* __restrict__ upart, int NCH, int ntiles)
{
    __shared__ float smem[SMEM_FLOATS];
    const int b    = blockIdx.y;
    const int c    = blockIdx.x;
    const int tid  = threadIdx.x;
    const int wv   = tid >> 6;
    const int lane = tid & 63;
    const int chunk = ntiles * TILE;
    const int fr   = (tid >> 1) & 3;
    const int AW   = R1_OFF + wv * (QN * 64);   // A: own 4KB slice of R1

    // Q -> LDS (scaled), ONE barrier; stages issued after it are never drained again
    {
        float4 qv = reinterpret_cast<const float4*>(query + (size_t)b * QN * DN)[tid];
        qv.x *= 0.125f; qv.y *= 0.125f; qv.z *= 0.125f; qv.w *= 0.125f;
        reinterpret_cast<float4*>(&smem[QS_OFF])[tid] = qv;
    }
    __syncthreads();

    {
        const float4* kb4 = reinterpret_cast<const float4*>(
            key + ((size_t)b * KTOT + c * chunk) * DN);
        STAGE_WV(R0_OFF, kb4, 0);   // tile0 q0
        STAGE_WV(R1_OFF, kb4, 4);   // tile0 q1
        __builtin_amdgcn_sched_barrier(0);
    }

    float U[QN];
    #pragma unroll
    for (int q = 0; q < QN; ++q) U[q] = 0.f;

    for (int t = 0; t < ntiles; ++t) {
        const int krow0 = c * chunk + t * TILE;
        const float4* kb4  = reinterpret_cast<const float4*>(
            key + ((size_t)b * KTOT + krow0) * DN);
        const float4* kb4n = kb4 + TILE * 16;                         // next tile
        const float*  vptr = value + ((size_t)b * KTOT + krow0 + wv * 64) * DN + lane;

        float s[QN];
        #pragma unroll
        for (int q = 0; q < QN; ++q) s[q] = 0.f;

        // ledger (wave-local, r9-proven): top of tile outstanding = stores(old)+q0(4)+q1(4)
        WAIT_VM(4);                                                   // q0 ready
        DOT_Q(0, R0_OFF);
        LGKM0(); STAGE_WV(R0_OFF, kb4, 8);                            // q2 -> R0
        __builtin_amdgcn_sched_barrier(0);

        WAIT_VM(4);                                                   // q1 ready (q2 may remain)
        DOT_Q(1, R1_OFF);
        LGKM0(); STAGE_WV(R1_OFF, kb4, 12);                           // q3 -> R1
        __builtin_amdgcn_sched_barrier(0);

        WAIT_VM(4);                                                   // q2 ready (q3 may remain)
        DOT_Q(2, R0_OFF);

        // V batch 0 (8 loads into 4 packed pairs) -> rides through dot q3 + softmax
        f2v va2[4];
        #pragma unroll
        for (int i = 0; i < 4; ++i) {
            va2[i].x = vptr[(size_t)(2 * i) * DN];
            va2[i].y = vptr[(size_t)(2 * i + 1) * DN];
        }
        __builtin_amdgcn_sched_barrier(0);
        WAIT_VM(8);                                                   // q3 ready (va 8 younger)
        DOT_Q(3, R1_OFF);

        // ---- softmax over the 16 queries (thread-local, k = krow0 + tid) ----
        float m = s[0];
        #pragma unroll
        for (int q = 1; q < QN; ++q) m = fmaxf(m, s[q]);
        float sum = 0.f;
        #pragma unroll
        for (int q = 0; q < QN; ++q) { s[q] = __expf(s[q] - m); sum += s[q]; }
        const float inv = 1.0f / sum;
        {
            float* ab = attn + (size_t)b * QN * KTOT + krow0 + tid;
            #pragma unroll
            for (int q = 0; q < QN; ++q) {
                const float a = s[q] * inv;
                __builtin_nontemporal_store(a, ab + (size_t)q * KTOT);
                smem[AW + q * 64 + lane] = a;        // own slice; dot-q3 reads already retired
            }
        }

        // ---- PV: packed 8-wide chains; U[q][lane=d] += a[q][k]*v[k][d] ----
        #pragma unroll 1
        for (int kk = 0; kk < 64; kk += 8) {
            f2v vb2[4];
            const int nxt = kk + 8;
            if (nxt < 64) {
                #pragma unroll
                for (int i = 0; i < 4; ++i) {
                    vb2[i].x = vptr[(size_t)(nxt + 2 * i) * DN];
                    vb2[i].y = vptr[(size_t)(nxt + 2 * i + 1) * DN];
                }
            }
            __builtin_amdgcn_s_setprio(1);
            #pragma unroll
            for (int q = 0; q < QN; ++q) {
                const f4v av0 = *(const f4v*)&smem[AW + q * 64 + kk];     // uniform bcast
                const f4v av1 = *(const f4v*)&smem[AW + q * 64 + kk + 4]; // uniform bcast
                f2v t;
                PK_MUL(t, av0.xy, va2[0]);
                PK_FMA(t, av0.zw, va2[1]);
                PK_FMA(t, av1.xy, va2[2]);
                PK_FMA(t, av1.zw, va2[3]);
                U[q] += t.x + t.y;
            }
            __builtin_amdgcn_s_setprio(0);
            #pragma unroll
            for (int i = 0; i < 4; ++i) va2[i] = vb2[i];
        }

        // next tile's q0,q1 issued at PV end (r9 schedule; hoist tested r11: neutral)
        if (t + 1 < ntiles) {
            LGKM0();
            STAGE_WV(R0_OFF, kb4n, 0);
            STAGE_WV(R1_OFF, kb4n, 4);
            __builtin_amdgcn_sched_barrier(0);
        }
    }

    // ---- block reduction: U across 4 waves (R0 region) ----
    __syncthreads();                                   // full drain (outside main loop)
    #pragma unroll
    for (int q = 0; q < QN; ++q)
        smem[R0_OFF + (wv * QN + q) * DN + lane] = U[q];
    __syncthreads();

    {
        const int q = tid >> 4, d0 = (tid & 15) * 4;
        const float4 r0 = *reinterpret_cast<const float4*>(&smem[R0_OFF + (0 * QN + q) * DN + d0]);
        const float4 r1 = *reinterpret_cast<const float4*>(&smem[R0_OFF + (1 * QN + q) * DN + d0]);
        const float4 r2 = *reinterpret_cast<const float4*>(&smem[R0_OFF + (2 * QN + q) * DN + d0]);
        const float4 r3 = *reinterpret_cast<const float4*>(&smem[R0_OFF + (3 * QN + q) * DN + d0]);
        float4 rs;
        rs.x = r0.x + r1.x + r2.x + r3.x;
        rs.y = r0.y + r1.y + r2.y + r3.y;
        rs.z = r0.z + r1.z + r2.z + r3.z;
        rs.w = r0.w + r1.w + r2.w + r3.w;
        *reinterpret_cast<float4*>(
            &upart[(((size_t)b * NCH + c) * QN + q) * DN + d0]) = rs;
    }
}

// ------------- k_norm: full-machine norm partials from the attn matrix -----------
// grid (8,16,8) = 1024 blocks (vs k3_fin's 128): the 33.5MB L3-resident sweep runs at
// full-device BW instead of half-occupancy. Each block sums an 8192-float slice of one
// (b,q) attn row -> normp2[(b*16+q)*8+z].
__global__ __launch_bounds__(256) void k_norm(
    const float* __restrict__ attn, float* __restrict__ normp2)
{
    const int b = blockIdx.x, q = blockIdx.y, z = blockIdx.z;
    const int tid = threadIdx.x;
    const float4* ap = reinterpret_cast<const float4*>(
        attn + ((size_t)b * QN + q) * KTOT + (size_t)z * 8192);
    float nv = 0.f;
    #pragma unroll
    for (int i = 0; i < 8; ++i) {
        const float4 a = ap[i * 256 + tid];          // fully coalesced
        nv += (a.x + a.y) + (a.z + a.w);
    }
    #pragma unroll
    for (int off = 1; off < 64; off <<= 1) nv += __shfl_xor(nv, off, 64);
    __shared__ float red[4];
    if ((tid & 63) == 0) red[tid >> 6] = nv;
    __syncthreads();
    if (tid == 0)
        normp2[((b * QN + q) << 3) + z] = red[0] + red[1] + red[2] + red[3];
}

// ------------- Finalize: out = sum_c U / (sum_z norm + eps); grid (8,16) -----------
__global__ __launch_bounds__(256) void k3_fin(
    const float* __restrict__ upart, const float* __restrict__ normp2,
    float* __restrict__ out, int NCH)
{
    const int b = blockIdx.x, q = blockIdx.y;
    const int tid = threadIdx.x;
    const int wv = tid >> 6, lane = tid & 63;

    // U: wave wv strides chunks, lane = d (coalesced)
    float acc = 0.f;
    for (int c = wv; c < NCH; c += 4)
        acc += upart[(((size_t)b * NCH + c) * QN + q) * DN + lane];
    __shared__ float ured[4][DN];
    ured[wv][lane] = acc;
    __syncthreads();

    if (tid < DN) {
        float n = 0.f;
        #pragma unroll
        for (int i = 0; i < 8; ++i)                  // uniform -> scalarized loads
            n += normp2[((b * QN + q) << 3) + i];
        const float inv = 1.0f / (n + 1e-8f);
        const float u   = ured[0][tid] + ured[1][tid] + ured[2][tid] + ured[3][tid];
        out[((size_t)b * QN + q) * DN + tid] = u * inv;
    }
}

extern "C" void kernel_launch(void* const* d_in, const int* in_sizes, int n_in,
                              void* d_out, int out_size, void* d_ws, size_t ws_size,
                              hipStream_t stream)
{
    const float* query = (const float*)d_in[0];
    const float* key   = (const float*)d_in[1];
    const float* value = (const float*)d_in[2];

    float* out  = (float*)d_out;                          // [8,16,64]
    float* attn = (float*)d_out + (size_t)BN * QN * DN;   // [8,1,16,65536]

    int NCH = 128;                                        // 1024 blocks (round-9 proven)
    while (NCH > 8 &&
           ((size_t)BN * NCH * QN * DN + BN * QN * 8) * 4 > ws_size) NCH >>= 1;
    const int ntiles = (KTOT / NCH) / TILE;

    float* upart  = (float*)d_ws;                         // [8][NCH][16][64]
    float* normp2 = (float*)d_ws + (size_t)BN * NCH * QN * DN;  // [8][16][8]

    fused_attn<<<dim3(NCH, BN), 256, 0, stream>>>(query, key, value, attn,
                                                  upart, NCH, ntiles);
    k_norm   <<<dim3(BN, QN, 8), 256, 0, stream>>>(attn, normp2);
    k3_fin   <<<dim3(BN, QN),    256, 0, stream>>>(upart, normp2, out, NCH);
}

// Round 18
// 77.006 us; speedup vs baseline: 1.0514x; 1.0012x over previous
//
#include <hip/hip_runtime.h>

#define KTOT 65536
#define QN 16
#define DN 64
#define BN 8
#define TILE 256

// smem layout (floats) — 9216 floats = 36,864 B
#define QS_OFF 0                    // Q scaled: [16][64]                 = 1024 floats
#define R0_OFF 1024                 // K quarter region 0: [256][16]      = 4096
#define R1_OFF 5120                 // K quarter region 1: [256][16]      = 4096
                                    // R1 doubles as A: per-wave [16][64] slices (wave-private)
#define SMEM_FLOATS 9216

typedef float f2v __attribute__((ext_vector_type(2)));
typedef float f4v __attribute__((ext_vector_type(4)));

// Packed dual-FP32 math (VOP3P, CDNA): d = a*b (lo,hi) / d += a*b (lo,hi).
#define PK_MUL(d, a, b) asm("v_pk_mul_f32 %0, %1, %2"     : "=v"(d) : "v"(a), "v"(b))
#define PK_FMA(d, a, b) asm("v_pk_fma_f32 %0, %1, %2, %0" : "+v"(d) : "v"(a), "v"(b))

// async global->LDS, 16B per lane; dest = wave-uniform base + lane*16
__device__ __forceinline__ void gload_lds16(const float* g, float* l)
{
    __builtin_amdgcn_global_load_lds(
        (const __attribute__((address_space(1))) void*)g,
        (__attribute__((address_space(3))) void*)l, 16, 0, 0);
}

// Counted wait. "memory" clobber = compiler fence: every op these waits must order
// (gload_lds, ds_read, global_load, stores) is a MEMORY op and cannot cross. Round-18:
// the sched_barrier(0)s that used to accompany these are REMOVED — they were redundant
// for correctness (rule #18's hazard applies to inline-asm ds_read results; all our LDS
// reads are compiler-generated with compiler-inserted lgkmcnt) and they fenced ~8
// scheduling regions per tile, blocking address-arith hoisting across wait boundaries.
#define WAIT_VM(N)  asm volatile("s_waitcnt vmcnt(" #N ")" ::: "memory")
#define LGKM0()     asm volatile("s_waitcnt lgkmcnt(0)" ::: "memory")

// WAVE-PRIVATE staging (verified r7/r9): wave wv stages ITS OWN rows 64wv..64wv+63
// of one K quarter (16 float cols; qo4 = quarter*4 in float4 units); exactly 4 gload_lds.
// Source pre-swizzled: global col = (lane&3) ^ ((row>>1)&3); read applies same XOR.
#define STAGE_WV(RX, kb4, qo4)                                                      \
    {                                                                               \
        _Pragma("unroll")                                                           \
        for (int j = 0; j < 4; ++j) {                                               \
            const int r_ = (wv << 6) + (j << 4) + (lane >> 2);                      \
            const int p_ = (lane & 3) ^ ((r_ >> 1) & 3);                            \
            gload_lds16((const float*)((kb4) + r_ * 16 + (qo4) + p_),               \
                        (float*)(((float4*)&smem[RX]) + ((wv << 8) + (j << 6) + lane))); \
        }                                                                           \
    }

// dot quarter qt: thread owns row tid; 16-wide packed chain per q (r15-proven).
#define DOT_Q(qt, RX)                                                               \
    {                                                                               \
        __builtin_amdgcn_s_setprio(1);                                              \
        f4v kvv[4];                                                                 \
        _Pragma("unroll")                                                           \
        for (int cc = 0; cc < 4; ++cc)                                              \
            kvv[cc] = ((const f4v*)&smem[RX])[tid * 4 + (cc ^ fr)];                 \
        _Pragma("unroll")                                                           \
        for (int q = 0; q < QN; ++q) {                                              \
            const f4v qv0 = *(const f4v*)&smem[QS_OFF + q * DN + (qt) * 16 + 0];    \
            const f4v qv1 = *(const f4v*)&smem[QS_OFF + q * DN + (qt) * 16 + 4];    \
            const f4v qv2 = *(const f4v*)&smem[QS_OFF + q * DN + (qt) * 16 + 8];    \
            const f4v qv3 = *(const f4v*)&smem[QS_OFF + q * DN + (qt) * 16 + 12];   \
            f2v t;                                                                  \
            PK_MUL(t, kvv[0].xy, qv0.xy);                                           \
            PK_FMA(t, kvv[0].zw, qv0.zw);                                           \
            PK_FMA(t, kvv[1].xy, qv1.xy);                                           \
            PK_FMA(t, kvv[1].zw, qv1.zw);                                           \
            PK_FMA(t, kvv[2].xy, qv2.xy);                                           \
            PK_FMA(t, kvv[2].zw, qv2.zw);                                           \
            PK_FMA(t, kvv[3].xy, qv3.xy);                                           \
            PK_FMA(t, kvv[3].zw, qv3.zw);                                           \
            s[q] += t.x + t.y;                                                      \
        }                                                                           \
        __builtin_amdgcn_s_setprio(0);                                              \
    }

// ------------- Fused: QK^T + softmax(Q) + attn write + PV partials ----------
// Round-18 = round 17 VERBATIM except all sched_barrier(0)s removed (see WAIT_VM note).
// Hardware ordering is carried entirely by the in-stream s_waitcnt instructions; the
// compiler may now hoist address arithmetic / V-load setup across wait boundaries.
__global__ __launch_bounds__(256, 3) void fused_attn(
    const float* __restrict__ query, const float* __restrict__ key,
    const float* __restrict__ value, float* __restrict__ attn,
    float* __restrict__ upart, int NCH, int ntiles)
{
    __shared__ float smem[SMEM_FLOATS];
    const int b    = blockIdx.y;
    const int c    = blockIdx.x;
    const int tid  = threadIdx.x;
    const int wv   = tid >> 6;
    const int lane = tid & 63;
    const int chunk = ntiles * TILE;
    const int fr   = (tid >> 1) & 3;
    const int AW   = R1_OFF + wv * (QN * 64);   // A: own 4KB slice of R1

    // Q -> LDS (scaled), ONE barrier; stages issued after it are never drained again
    {
        float4 qv = reinterpret_cast<const float4*>(query + (size_t)b * QN * DN)[tid];
        qv.x *= 0.125f; qv.y *= 0.125f; qv.z *= 0.125f; qv.w *= 0.125f;
        reinterpret_cast<float4*>(&smem[QS_OFF])[tid] = qv;
    }
    __syncthreads();

    {
        const float4* kb4 = reinterpret_cast<const float4*>(
            key + ((size_t)b * KTOT + c * chunk) * DN);
        STAGE_WV(R0_OFF, kb4, 0);   // tile0 q0
        STAGE_WV(R1_OFF, kb4, 4);   // tile0 q1
    }

    float U[QN];
    #pragma unroll
    for (int q = 0; q < QN; ++q) U[q] = 0.f;

    for (int t = 0; t < ntiles; ++t) {
        const int krow0 = c * chunk + t * TILE;
        const float4* kb4  = reinterpret_cast<const float4*>(
            key + ((size_t)b * KTOT + krow0) * DN);
        const float4* kb4n = kb4 + TILE * 16;                         // next tile
        const float*  vptr = value + ((size_t)b * KTOT + krow0 + wv * 64) * DN + lane;

        float s[QN];
        #pragma unroll
        for (int q = 0; q < QN; ++q) s[q] = 0.f;

        // ledger (wave-local, r9-proven): top of tile outstanding = stores(old)+q0(4)+q1(4)
        WAIT_VM(4);                                                   // q0 ready
        DOT_Q(0, R0_OFF);
        LGKM0(); STAGE_WV(R0_OFF, kb4, 8);                            // q2 -> R0

        WAIT_VM(4);                                                   // q1 ready (q2 may remain)
        DOT_Q(1, R1_OFF);
        LGKM0(); STAGE_WV(R1_OFF, kb4, 12);                           // q3 -> R1

        WAIT_VM(4);                                                   // q2 ready (q3 may remain)
        DOT_Q(2, R0_OFF);

        // V batch 0 (8 loads into 4 packed pairs) -> rides through dot q3 + softmax
        f2v va2[4];
        #pragma unroll
        for (int i = 0; i < 4; ++i) {
            va2[i].x = vptr[(size_t)(2 * i) * DN];
            va2[i].y = vptr[(size_t)(2 * i + 1) * DN];
        }
        WAIT_VM(8);                                                   // q3 ready (va 8 younger)
        DOT_Q(3, R1_OFF);

        // ---- softmax over the 16 queries (thread-local, k = krow0 + tid) ----
        float m = s[0];
        #pragma unroll
        for (int q = 1; q < QN; ++q) m = fmaxf(m, s[q]);
        float sum = 0.f;
        #pragma unroll
        for (int q = 0; q < QN; ++q) { s[q] = __expf(s[q] - m); sum += s[q]; }
        const float inv = 1.0f / sum;
        {
            float* ab = attn + (size_t)b * QN * KTOT + krow0 + tid;
            #pragma unroll
            for (int q = 0; q < QN; ++q) {
                const float a = s[q] * inv;
                __builtin_nontemporal_store(a, ab + (size_t)q * KTOT);
                smem[AW + q * 64 + lane] = a;        // own slice; dot-q3 reads already retired
            }
        }

        // ---- PV: packed 8-wide chains; U[q][lane=d] += a[q][k]*v[k][d] ----
        #pragma unroll 1
        for (int kk = 0; kk < 64; kk += 8) {
            f2v vb2[4];
            const int nxt = kk + 8;
            if (nxt < 64) {
                #pragma unroll
                for (int i = 0; i < 4; ++i) {
                    vb2[i].x = vptr[(size_t)(nxt + 2 * i) * DN];
                    vb2[i].y = vptr[(size_t)(nxt + 2 * i + 1) * DN];
                }
            }
            __builtin_amdgcn_s_setprio(1);
            #pragma unroll
            for (int q = 0; q < QN; ++q) {
                const f4v av0 = *(const f4v*)&smem[AW + q * 64 + kk];     // uniform bcast
                const f4v av1 = *(const f4v*)&smem[AW + q * 64 + kk + 4]; // uniform bcast
                f2v t;
                PK_MUL(t, av0.xy, va2[0]);
                PK_FMA(t, av0.zw, va2[1]);
                PK_FMA(t, av1.xy, va2[2]);
                PK_FMA(t, av1.zw, va2[3]);
                U[q] += t.x + t.y;
            }
            __builtin_amdgcn_s_setprio(0);
            #pragma unroll
            for (int i = 0; i < 4; ++i) va2[i] = vb2[i];
        }

        // next tile's q0,q1 issued at PV end (r9 schedule; hoist tested r11: neutral)
        if (t + 1 < ntiles) {
            LGKM0();
            STAGE_WV(R0_OFF, kb4n, 0);
            STAGE_WV(R1_OFF, kb4n, 4);
        }
    }

    // ---- block reduction: U across 4 waves (R0 region) ----
    __syncthreads();                                   // full drain (outside main loop)
    #pragma unroll
    for (int q = 0; q < QN; ++q)
        smem[R0_OFF + (wv * QN + q) * DN + lane] = U[q];
    __syncthreads();

    {
        const int q = tid >> 4, d0 = (tid & 15) * 4;
        const float4 r0 = *reinterpret_cast<const float4*>(&smem[R0_OFF + (0 * QN + q) * DN + d0]);
        const float4 r1 = *reinterpret_cast<const float4*>(&smem[R0_OFF + (1 * QN + q) * DN + d0]);
        const float4 r2 = *reinterpret_cast<const float4*>(&smem[R0_OFF + (2 * QN + q) * DN + d0]);
        const float4 r3 = *reinterpret_cast<const float4*>(&smem[R0_OFF + (3 * QN + q) * DN + d0]);
        float4 rs;
        rs.x = r0.x + r1.x + r2.x + r3.x;
        rs.y = r0.y + r1.y + r2.y + r3.y;
        rs.z = r0.z + r1.z + r2.z + r3.z;
        rs.w = r0.w + r1.w + r2.w + r3.w;
        *reinterpret_cast<float4*>(
            &upart[(((size_t)b * NCH + c) * QN + q) * DN + d0]) = rs;
    }
}

// ------------- k_norm: full-machine norm partials from the attn matrix -----------
// grid (8,16,8) = 1024 blocks: the 33.5MB L3-resident sweep at full-device BW (r17: -3.7us).
__global__ __launch_bounds__(256) void k_norm(
    const float* __restrict__ attn, float* __restrict__ normp2)
{
    const int b = blockIdx.x, q = blockIdx.y, z = blockIdx.z;
    const int tid = threadIdx.x;
    const float4* ap = reinterpret_cast<const float4*>(
        attn + ((size_t)b * QN + q) * KTOT + (size_t)z * 8192);
    float nv = 0.f;
    #pragma unroll
    for (int i = 0; i < 8; ++i) {
        const float4 a = ap[i * 256 + tid];          // fully coalesced
        nv += (a.x + a.y) + (a.z + a.w);
    }
    #pragma unroll
    for (int off = 1; off < 64; off <<= 1) nv += __shfl_xor(nv, off, 64);
    __shared__ float red[4];
    if ((tid & 63) == 0) red[tid >> 6] = nv;
    __syncthreads();
    if (tid == 0)
        normp2[((b * QN + q) << 3) + z] = red[0] + red[1] + red[2] + red[3];
}

// ------------- Finalize: out = sum_c U / (sum_z norm + eps); grid (8,16) -----------
__global__ __launch_bounds__(256) void k3_fin(
    const float* __restrict__ upart, const float* __restrict__ normp2,
    float* __restrict__ out, int NCH)
{
    const int b = blockIdx.x, q = blockIdx.y;
    const int tid = threadIdx.x;
    const int wv = tid >> 6, lane = tid & 63;

    // U: wave wv strides chunks, lane = d (coalesced)
    float acc = 0.f;
    for (int c = wv; c < NCH; c += 4)
        acc += upart[(((size_t)b * NCH + c) * QN + q) * DN + lane];
    __shared__ float ured[4][DN];
    ured[wv][lane] = acc;
    __syncthreads();

    if (tid < DN) {
        float n = 0.f;
        #pragma unroll
        for (int i = 0; i < 8; ++i)                  // uniform -> scalarized loads
            n += normp2[((b * QN + q) << 3) + i];
        const float inv = 1.0f / (n + 1e-8f);
        const float u   = ured[0][tid] + ured[1][tid] + ured[2][tid] + ured[3][tid];
        out[((size_t)b * QN + q) * DN + tid] = u * inv;
    }
}

extern "C" void kernel_launch(void* const* d_in, const int* in_sizes, int n_in,
                              void* d_out, int out_size, void* d_ws, size_t ws_size,
                              hipStream_t stream)
{
    const float* query = (const float*)d_in[0];
    const float* key   = (const float*)d_in[1];
    const float* value = (const float*)d_in[2];

    float* out  = (float*)d_out;                          // [8,16,64]
    float* attn = (float*)d_out + (size_t)BN * QN * DN;   // [8,1,16,65536]

    int NCH = 128;                                        // 1024 blocks (round-9 proven)
    while (NCH > 8 &&
           ((size_t)BN * NCH * QN * DN + BN * QN * 8) * 4 > ws_size) NCH >>= 1;
    const int ntiles = (KTOT / NCH) / TILE;

    float* upart  = (float*)d_ws;                         // [8][NCH][16][64]
    float* normp2 = (float*)d_ws + (size_t)BN * NCH * QN * DN;  // [8][16][8]

    fused_attn<<<dim3(NCH, BN), 256, 0, stream>>>(query, key, value, attn,
                                                  upart, NCH, ntiles);
    k_norm   <<<dim3(BN, QN, 8), 256, 0, stream>>>(attn, normp2);
    k3_fin   <<<dim3(BN, QN),    256, 0, stream>>>(upart, normp2, out, NCH);
}